// Round 3
// baseline (6566.915 us; speedup 1.0000x reference)
//
#include <hip/hip_runtime.h>
#include <stdint.h>

// ---------- types ----------
typedef short short8v __attribute__((ext_vector_type(8)));
typedef float f32x4  __attribute__((ext_vector_type(4)));
typedef unsigned long long u64;

__device__ inline uint16_t f2bf(float f){
  uint32_t u = __float_as_uint(f);
  uint32_t r = (u + 0x7fffu + ((u >> 16) & 1u)) >> 16;
  return (uint16_t)r;
}
__device__ inline float bf2f(uint16_t h){
  return __uint_as_float(((uint32_t)h) << 16);
}

// ---------- f32 -> bf16 conversion (vectorized) ----------
__global__ void cvt_f32_bf16(const float* __restrict__ src, uint16_t* __restrict__ dst, int n4){
  int i = blockIdx.x * blockDim.x + threadIdx.x;
  int stride = gridDim.x * blockDim.x;
  for (; i < n4; i += stride){
    float4 v = ((const float4*)src)[i];
    uint64_t p = (uint64_t)f2bf(v.x)
               | ((uint64_t)f2bf(v.y) << 16)
               | ((uint64_t)f2bf(v.z) << 32)
               | ((uint64_t)f2bf(v.w) << 48);
    ((uint64_t*)dst)[i] = p;
  }
}

// ---------- bf16 GEMM: C[m,n] = sum_k A[m,k] * Bw[n,k] + bias[n]  (C bf16) ----------
#define GL2LDS(g, l) __builtin_amdgcn_global_load_lds((const __attribute__((address_space(1))) unsigned int*)(g), (__attribute__((address_space(3))) unsigned int*)(l), 16, 0, 0)

__global__ __launch_bounds__(256) void gemm_bt_bias(
    const uint16_t* __restrict__ A, const uint16_t* __restrict__ Bw,
    const float* __restrict__ bias, uint16_t* __restrict__ C,
    int M, int N, int K)
{
  __shared__ uint16_t As[128 * 64];
  __shared__ uint16_t Bs[128 * 64];
  const int tid  = threadIdx.x;
  const int lane = tid & 63, wid = tid >> 6;
  const int n0 = blockIdx.x * 128, m0 = blockIdx.y * 128;
  const int wrow = (wid & 1) * 64, wcol = (wid >> 1) * 64;
  const int l15 = lane & 15, l4 = lane >> 4;
  const int srow = lane >> 3, scol = (lane & 7) * 8;
  const size_t Ks = (size_t)K;

  f32x4 acc[4][4] = {};

  for (int kt = 0; kt < K; kt += 64){
    __syncthreads();
    const uint16_t* gA = A  + (size_t)m0 * Ks + kt;
    const uint16_t* gB = Bw + (size_t)n0 * Ks + kt;
    #pragma unroll
    for (int i = 0; i < 4; ++i){
      int rb = wid * 32 + i * 8;
      GL2LDS(gA + (size_t)(rb + srow) * Ks + scol, &As[rb * 64]);
      GL2LDS(gB + (size_t)(rb + srow) * Ks + scol, &Bs[rb * 64]);
    }
    __syncthreads();
    #pragma unroll
    for (int kk = 0; kk < 2; ++kk){
      short8v a[4], b[4];
      int koff = kk * 32 + l4 * 8;
      #pragma unroll
      for (int mt = 0; mt < 4; ++mt) a[mt] = *(const short8v*)&As[(wrow + mt*16 + l15) * 64 + koff];
      #pragma unroll
      for (int nt = 0; nt < 4; ++nt) b[nt] = *(const short8v*)&Bs[(wcol + nt*16 + l15) * 64 + koff];
      #pragma unroll
      for (int mt = 0; mt < 4; ++mt)
        #pragma unroll
        for (int nt = 0; nt < 4; ++nt)
          acc[mt][nt] = __builtin_amdgcn_mfma_f32_16x16x32_bf16(a[mt], b[nt], acc[mt][nt], 0, 0, 0);
    }
  }
  #pragma unroll
  for (int mt = 0; mt < 4; ++mt)
    #pragma unroll
    for (int nt = 0; nt < 4; ++nt){
      int col = n0 + wcol + nt * 16 + l15;
      float bv = bias[col];
      int rbase = m0 + wrow + mt * 16 + l4 * 4;
      #pragma unroll
      for (int j = 0; j < 4; ++j)
        C[(size_t)(rbase + j) * (size_t)N + col] = f2bf(acc[mt][nt][j] + bv);
    }
}

// LDS reduce buffer index with XOR swizzle (keeps f32x4 alignment)
__device__ inline int ridx(int w, int c, int m){
  return (w * 48 + c) * 68 + (m ^ ((c & 7) << 2));
}

// ---------- persistent bidirectional GRU layer (fence-free) ----------
// grid = 128 blocks: dir = blk>>6, columns c0 = (blk&63)*16 of H.
// h state moves through agent-scope RELAXED u64 atomics (sc1, L2-bypassing,
// coherent at fabric/MALL) -> no buffer_wbl2/buffer_inv in the loop.
__global__ __launch_bounds__(256, 1) void gru_layer(
    const uint16_t* __restrict__ xp,   // (T,B,3H) bf16 (bias already added)
    const uint16_t* __restrict__ U,    // (3H, H) bf16, rows: Ur | Uz | Un
    const float* __restrict__ bn,      // (H)
    u64* __restrict__ hbuf,            // [2 parity][2 dir][64 rows][256 u64] (4 bf16/u64)
    uint16_t* __restrict__ out_bf,     // (T,B,2H) bf16 or null
    float* __restrict__ out_f32,       // (T,B,2H) f32 or null
    float* __restrict__ hid,           // 2 slots of (64,1024) f32: fwd then bwd
    unsigned* __restrict__ flags)      // [2 dir][64] stride-4 u32
{
  __shared__ float red[4 * 48 * 68];
  const int tid  = threadIdx.x;
  const int lane = tid & 63, wid = tid >> 6;
  const int dir  = blockIdx.x >> 6;
  const int blkc = blockIdx.x & 63;
  const int c0   = blkc * 16;
  const int l15 = lane & 15, l4 = lane >> 4;
  unsigned* myflags = flags + dir * 256;

  // register-resident B fragments (U weights), reused for all 256 steps
  short8v bfr[3][8];
  #pragma unroll
  for (int g = 0; g < 3; ++g)
    #pragma unroll
    for (int k32 = 0; k32 < 8; ++k32){
      int row = g * 1024 + c0 + l15;
      int k   = wid * 256 + k32 * 32 + l4 * 8;
      bfr[g][k32] = *(const short8v*)&U[(size_t)row * 1024 + k];
    }

  // gate mapping: thread -> (row gm, 4 consecutive cols gc..gc+3)
  const int g4 = tid & 3, gm = tid >> 2;
  const int gc = c0 + g4 * 4;
  float hold[4] = {0.f, 0.f, 0.f, 0.f};
  float bnv[4];
  #pragma unroll
  for (int j = 0; j < 4; ++j) bnv[j] = bn[gc + j];

  // prefetch xp for step 0 (u64 = 4 bf16, cols gc..gc+3)
  u64 pxr, pxz, pxn;
  {
    int t0 = dir ? 255 : 0;
    size_t xb2 = ((size_t)t0 * 64 + gm) * 3072 + gc;
    pxr = *(const u64*)&xp[xb2];
    pxz = *(const u64*)&xp[xb2 + 1024];
    pxn = *(const u64*)&xp[xb2 + 2048];
  }

  for (int s = 0; s < 256; ++s){
    const int par = s & 1;
    const int t = dir ? (255 - s) : s;

    f32x4 acc[3][4] = {};
    if (s > 0){
      // ---- wait: all blocks of this direction have finished step s-1 ----
      if (wid == 0){
        const unsigned tgt = (unsigned)s;
        int spins = 0;
        for (;;){
          unsigned v = __hip_atomic_load(&myflags[lane * 4], __ATOMIC_RELAXED, __HIP_MEMORY_SCOPE_AGENT);
          if (__all((int)(v >= tgt))) break;
          __builtin_amdgcn_s_sleep(1);
          if (((++spins) & 1023) == 0)
            __builtin_amdgcn_fence(__ATOMIC_ACQUIRE, "agent");   // deadlock safety valve
        }
      }
      __syncthreads();

      const u64* hb = hbuf + (size_t)(par * 2 + dir) * (64 * 256);
      #pragma unroll
      for (int k32 = 0; k32 < 8; ++k32){
        short8v af[4];
        int kq = wid * 64 + k32 * 8 + l4 * 2;   // u64 index within row
        #pragma unroll
        for (int mt = 0; mt < 4; ++mt){
          size_t rb = (size_t)(mt * 16 + l15) * 256 + kq;
          u64 lo = __hip_atomic_load(&hb[rb],     __ATOMIC_RELAXED, __HIP_MEMORY_SCOPE_AGENT);
          u64 hi = __hip_atomic_load(&hb[rb + 1], __ATOMIC_RELAXED, __HIP_MEMORY_SCOPE_AGENT);
          union { u64 q[2]; short8v v; } uu;
          uu.q[0] = lo; uu.q[1] = hi;
          af[mt] = uu.v;
        }
        #pragma unroll
        for (int g = 0; g < 3; ++g)
          #pragma unroll
          for (int mt = 0; mt < 4; ++mt)
            acc[g][mt] = __builtin_amdgcn_mfma_f32_16x16x32_bf16(af[mt], bfr[g][k32], acc[g][mt], 0, 0, 0);
      }
    }

    // write partial sums to LDS (m-contiguous, swizzled)
    #pragma unroll
    for (int g = 0; g < 3; ++g)
      #pragma unroll
      for (int mt = 0; mt < 4; ++mt)
        *(f32x4*)&red[ridx(wid, g * 16 + l15, mt * 16 + l4 * 4)] = acc[g][mt];
    __syncthreads();

    // reduce over 4 waves; thread -> (row gm, cols g4*4..+3)
    float ra[4] = {}, za[4] = {}, na[4] = {};
    #pragma unroll
    for (int w = 0; w < 4; ++w)
      #pragma unroll
      for (int j = 0; j < 4; ++j){
        ra[j] += red[ridx(w,      g4 * 4 + j, gm)];
        za[j] += red[ridx(w, 16 + g4 * 4 + j, gm)];
        na[j] += red[ridx(w, 32 + g4 * 4 + j, gm)];
      }

    u64 hv = 0;
    float hn[4];
    #pragma unroll
    for (int j = 0; j < 4; ++j){
      float xr = bf2f((uint16_t)(pxr >> (16 * j)));
      float xz = bf2f((uint16_t)(pxz >> (16 * j)));
      float xn = bf2f((uint16_t)(pxn >> (16 * j)));
      float r = 1.f / (1.f + __expf(-(xr + ra[j])));
      float z = 1.f / (1.f + __expf(-(xz + za[j])));
      float n = tanhf(xn + r * (na[j] + bnv[j]));
      hn[j] = (1.f - z) * n + z * hold[j];
      hold[j] = hn[j];
      hv |= ((u64)f2bf(hn[j])) << (16 * j);
    }

    // h store: parity (s+1)&1, agent-relaxed atomic (sc1)
    {
      u64* hw = hbuf + (size_t)(((par ^ 1) * 2) + dir) * (64 * 256);
      __hip_atomic_store(&hw[(size_t)gm * 256 + (c0 >> 2) + g4], hv, __ATOMIC_RELAXED, __HIP_MEMORY_SCOPE_AGENT);
    }
    // output store
    {
      size_t obase = ((size_t)t * 64 + gm) * 2048 + (size_t)dir * 1024 + gc;
      if (out_bf) __builtin_nontemporal_store(hv, (u64*)&out_bf[obase]);
      else {
        f32x4 ov = { hn[0], hn[1], hn[2], hn[3] };
        __builtin_nontemporal_store(ov, (f32x4*)&out_f32[obase]);
      }
      if (s == 255){
        f32x4 hvv = { hn[0], hn[1], hn[2], hn[3] };
        *(f32x4*)&hid[((size_t)dir * 64 + gm) * 1024 + gc] = hvv;
      }
    }

    __syncthreads();   // compiler drains vmcnt(0) per wave before s_barrier -> h stores committed
    if (s < 255){
      if (tid == 0)
        __hip_atomic_store(&myflags[blkc * 4], (unsigned)(s + 1), __ATOMIC_RELAXED, __HIP_MEMORY_SCOPE_AGENT);
      // prefetch next-step xp; overlaps with next poll wait
      int tn = dir ? (255 - (s + 1)) : (s + 1);
      size_t xb2 = ((size_t)tn * 64 + gm) * 3072 + gc;
      pxr = *(const u64*)&xp[xb2];
      pxz = *(const u64*)&xp[xb2 + 1024];
      pxn = *(const u64*)&xp[xb2 + 2048];
    }
  }
}

// ---------- host ----------
extern "C" void kernel_launch(void* const* d_in, const int* in_sizes, int n_in,
                              void* d_out, int out_size, void* d_ws, size_t ws_size,
                              hipStream_t stream) {
  const float* x   = (const float*)d_in[0];
  const float* W0  = (const float*)d_in[1];
  const float* b0  = (const float*)d_in[2];
  const float* Ur0 = (const float*)d_in[3];
  const float* Uz0 = (const float*)d_in[4];
  const float* Un0 = (const float*)d_in[5];
  const float* bn0 = (const float*)d_in[6];
  const float* W1  = (const float*)d_in[7];
  const float* b1  = (const float*)d_in[8];
  const float* Ur1 = (const float*)d_in[9];
  const float* Uz1 = (const float*)d_in[10];
  const float* Un1 = (const float*)d_in[11];
  const float* bn1 = (const float*)d_in[12];
  float* out = (float*)d_out;

  char* base = (char*)d_ws;
  unsigned* ctr0 = (unsigned*)base;                  // layer0 flags (2 dirs * 1KB)
  unsigned* ctr1 = (unsigned*)(base + 4096);         // layer1 flags
  uint16_t* xb    = (uint16_t*)(base + 8192);
  uint16_t* w0b   = xb    + (size_t)16384 * 1024;
  uint16_t* u0b   = w0b   + (size_t)3072 * 1024;
  uint16_t* w1b   = u0b   + (size_t)3072 * 1024;
  uint16_t* u1b   = w1b   + (size_t)3072 * 2048;
  uint16_t* xp    = u1b   + (size_t)3072 * 1024;
  uint16_t* out0b = xp    + (size_t)16384 * 3072;
  u64*      hbuf  = (u64*)(out0b + (size_t)16384 * 2048);

  hipMemsetAsync(d_ws, 0, 8192, stream);

  auto cvt = [&](const float* s, uint16_t* d, size_t n){
    int n4 = (int)(n / 4);
    int grid = (n4 + 255) / 256; if (grid > 2048) grid = 2048;
    hipLaunchKernelGGL(cvt_f32_bf16, dim3(grid), dim3(256), 0, stream, s, d, n4);
  };
  cvt(x,   xb,  (size_t)16384 * 1024);
  cvt(W0,  w0b, (size_t)3072 * 1024);
  cvt(Ur0, u0b + 0 * (size_t)1024 * 1024, (size_t)1024 * 1024);
  cvt(Uz0, u0b + 1 * (size_t)1024 * 1024, (size_t)1024 * 1024);
  cvt(Un0, u0b + 2 * (size_t)1024 * 1024, (size_t)1024 * 1024);
  cvt(W1,  w1b, (size_t)3072 * 2048);
  cvt(Ur1, u1b + 0 * (size_t)1024 * 1024, (size_t)1024 * 1024);
  cvt(Uz1, u1b + 1 * (size_t)1024 * 1024, (size_t)1024 * 1024);
  cvt(Un1, u1b + 2 * (size_t)1024 * 1024, (size_t)1024 * 1024);

  // layer 0: xp0 = x @ W0^T + b0
  hipLaunchKernelGGL(gemm_bt_bias, dim3(24, 128), dim3(256), 0, stream,
                     xb, w0b, b0, xp, 16384, 3072, 1024);
  // layer 0 recurrence -> out0b (bf16), hidden slots 0,1
  hipLaunchKernelGGL(gru_layer, dim3(128), dim3(256), 0, stream,
                     xp, u0b, bn0, hbuf,
                     out0b, (float*)nullptr,
                     out + (size_t)33554432, ctr0);
  // layer 1: xp1 = out0 @ W1^T + b1
  hipLaunchKernelGGL(gemm_bt_bias, dim3(24, 128), dim3(256), 0, stream,
                     out0b, w1b, b1, xp, 16384, 3072, 2048);
  // layer 1 recurrence -> d_out (f32), hidden slots 2,3
  hipLaunchKernelGGL(gru_layer, dim3(128), dim3(256), 0, stream,
                     xp, u1b, bn1, hbuf,
                     (uint16_t*)nullptr, out,
                     out + (size_t)33554432 + (size_t)2 * 64 * 1024, ctr1);
}

// Round 4
// 4147.969 us; speedup vs baseline: 1.5832x; 1.5832x over previous
//
#include <hip/hip_runtime.h>
#include <stdint.h>

// ---------- types ----------
typedef short short8v __attribute__((ext_vector_type(8)));
typedef float f32x4  __attribute__((ext_vector_type(4)));
typedef unsigned long long u64;

__device__ inline uint16_t f2bf(float f){
  uint32_t u = __float_as_uint(f);
  uint32_t r = (u + 0x7fffu + ((u >> 16) & 1u)) >> 16;
  return (uint16_t)r;
}
__device__ inline float bf2f(uint16_t h){
  return __uint_as_float(((uint32_t)h) << 16);
}

// ---------- f32 -> bf16 conversion (vectorized) ----------
__global__ void cvt_f32_bf16(const float* __restrict__ src, uint16_t* __restrict__ dst, int n4){
  int i = blockIdx.x * blockDim.x + threadIdx.x;
  int stride = gridDim.x * blockDim.x;
  for (; i < n4; i += stride){
    float4 v = ((const float4*)src)[i];
    uint64_t p = (uint64_t)f2bf(v.x)
               | ((uint64_t)f2bf(v.y) << 16)
               | ((uint64_t)f2bf(v.z) << 32)
               | ((uint64_t)f2bf(v.w) << 48);
    ((uint64_t*)dst)[i] = p;
  }
}

// ---------- bf16 GEMM: C[m,n] = sum_k A[m,k] * Bw[n,k] + bias[n]  (C bf16) ----------
#define GL2LDS(g, l) __builtin_amdgcn_global_load_lds((const __attribute__((address_space(1))) unsigned int*)(g), (__attribute__((address_space(3))) unsigned int*)(l), 16, 0, 0)

__global__ __launch_bounds__(256) void gemm_bt_bias(
    const uint16_t* __restrict__ A, const uint16_t* __restrict__ Bw,
    const float* __restrict__ bias, uint16_t* __restrict__ C,
    int M, int N, int K)
{
  __shared__ uint16_t As[128 * 64];
  __shared__ uint16_t Bs[128 * 64];
  const int tid  = threadIdx.x;
  const int lane = tid & 63, wid = tid >> 6;
  const int n0 = blockIdx.x * 128, m0 = blockIdx.y * 128;
  const int wrow = (wid & 1) * 64, wcol = (wid >> 1) * 64;
  const int l15 = lane & 15, l4 = lane >> 4;
  const int srow = lane >> 3, scol = (lane & 7) * 8;
  const size_t Ks = (size_t)K;

  f32x4 acc[4][4] = {};

  for (int kt = 0; kt < K; kt += 64){
    __syncthreads();
    const uint16_t* gA = A  + (size_t)m0 * Ks + kt;
    const uint16_t* gB = Bw + (size_t)n0 * Ks + kt;
    #pragma unroll
    for (int i = 0; i < 4; ++i){
      int rb = wid * 32 + i * 8;
      GL2LDS(gA + (size_t)(rb + srow) * Ks + scol, &As[rb * 64]);
      GL2LDS(gB + (size_t)(rb + srow) * Ks + scol, &Bs[rb * 64]);
    }
    __syncthreads();
    #pragma unroll
    for (int kk = 0; kk < 2; ++kk){
      short8v a[4], b[4];
      int koff = kk * 32 + l4 * 8;
      #pragma unroll
      for (int mt = 0; mt < 4; ++mt) a[mt] = *(const short8v*)&As[(wrow + mt*16 + l15) * 64 + koff];
      #pragma unroll
      for (int nt = 0; nt < 4; ++nt) b[nt] = *(const short8v*)&Bs[(wcol + nt*16 + l15) * 64 + koff];
      #pragma unroll
      for (int mt = 0; mt < 4; ++mt)
        #pragma unroll
        for (int nt = 0; nt < 4; ++nt)
          acc[mt][nt] = __builtin_amdgcn_mfma_f32_16x16x32_bf16(a[mt], b[nt], acc[mt][nt], 0, 0, 0);
    }
  }
  #pragma unroll
  for (int mt = 0; mt < 4; ++mt)
    #pragma unroll
    for (int nt = 0; nt < 4; ++nt){
      int col = n0 + wcol + nt * 16 + l15;
      float bv = bias[col];
      int rbase = m0 + wrow + mt * 16 + l4 * 4;
      #pragma unroll
      for (int j = 0; j < 4; ++j)
        C[(size_t)(rbase + j) * (size_t)N + col] = f2bf(acc[mt][nt][j] + bv);
    }
}

// LDS reduce buffer index with XOR swizzle (keeps f32x4 alignment)
__device__ inline int ridx(int w, int c, int m){
  return (w * 48 + c) * 68 + (m ^ ((c & 7) << 2));
}

// 16B MALL-direct load: bypass L1 (sc0) and L2 (sc1); "memory" clobber keeps
// compiler memory ops from interleaving into our hand-counted vmcnt window.
#define HLOAD(dst, addr) \
  asm volatile("global_load_dwordx4 %0, %1, off sc0 sc1" : "=v"(dst) : "v"(addr) : "memory")

// ---------- persistent bidirectional GRU layer (fence-free) ----------
// grid = 128 blocks: dir = blk>>6, columns c0 = (blk&63)*16 of H.
// h stores: relaxed agent atomic u64 (proven to reach coherence point).
// h loads: coalesced dwordx4 sc0+sc1 (MALL-direct, cacheline-granular).
// No fences in the loop.
__global__ __launch_bounds__(256, 1) void gru_layer(
    const uint16_t* __restrict__ xp,   // (T,B,3H) bf16 (bias already added)
    const uint16_t* __restrict__ U,    // (3H, H) bf16, rows: Ur | Uz | Un
    const float* __restrict__ bn,      // (H)
    u64* __restrict__ hbuf,            // [2 parity][2 dir][64 rows][256 u64]
    uint16_t* __restrict__ out_bf,     // (T,B,2H) bf16 or null
    float* __restrict__ out_f32,       // (T,B,2H) f32 or null
    float* __restrict__ hid,           // 2 slots of (64,1024) f32: fwd then bwd
    unsigned* __restrict__ flags)      // [2 dir][64] stride-4 u32
{
  __shared__ float red[4 * 48 * 68];
  const int tid  = threadIdx.x;
  const int lane = tid & 63, wid = tid >> 6;
  const int dir  = blockIdx.x >> 6;
  const int blkc = blockIdx.x & 63;
  const int c0   = blkc * 16;
  const int l15 = lane & 15, l4 = lane >> 4;
  unsigned* myflags = flags + dir * 256;

  // register-resident B fragments (U weights), reused for all 256 steps
  short8v bfr[3][8];
  #pragma unroll
  for (int g = 0; g < 3; ++g)
    #pragma unroll
    for (int k32 = 0; k32 < 8; ++k32){
      int row = g * 1024 + c0 + l15;
      int k   = wid * 256 + k32 * 32 + l4 * 8;
      bfr[g][k32] = *(const short8v*)&U[(size_t)row * 1024 + k];
    }

  // gate mapping: thread -> (row gm, 4 consecutive cols gc..gc+3)
  const int g4 = tid & 3, gm = tid >> 2;
  const int gc = c0 + g4 * 4;
  float hold[4] = {0.f, 0.f, 0.f, 0.f};
  float bnv[4];
  #pragma unroll
  for (int j = 0; j < 4; ++j) bnv[j] = bn[gc + j];

  // per-thread h-load geometry: row (mt*16+l15), k base = wid*256 + l4*8
  const int kc = wid * 256 + l4 * 8;

  // prefetch xp for step 0 (u64 = 4 bf16, cols gc..gc+3)
  u64 pxr, pxz, pxn;
  {
    int t0 = dir ? 255 : 0;
    size_t xb2 = ((size_t)t0 * 64 + gm) * 3072 + gc;
    pxr = *(const u64*)&xp[xb2];
    pxz = *(const u64*)&xp[xb2 + 1024];
    pxn = *(const u64*)&xp[xb2 + 2048];
  }

  for (int s = 0; s < 256; ++s){
    const int par = s & 1;
    const int t = dir ? (255 - s) : s;

    f32x4 acc[3][4] = {};
    if (s > 0){
      // ---- wait: all blocks of this direction have finished step s-1 ----
      if (wid == 0){
        const unsigned tgt = (unsigned)s;
        int spins = 0;
        for (;;){
          unsigned v = __hip_atomic_load(&myflags[lane * 4], __ATOMIC_RELAXED, __HIP_MEMORY_SCOPE_AGENT);
          if (__all((int)(v >= tgt))) break;
          __builtin_amdgcn_s_sleep(1);
          if (((++spins) & 1023) == 0)
            __builtin_amdgcn_fence(__ATOMIC_ACQUIRE, "agent");   // deadlock safety valve
        }
      }
      __syncthreads();

      const uint16_t* hbase = (const uint16_t*)hbuf + (size_t)(par * 2 + dir) * (64 * 1024);

      // ---- K-loop: depth-4 pipelined MALL-direct loads + MFMA ----
      short8v hc[8][4];
      #pragma unroll
      for (int c = 0; c < 3; ++c)
        #pragma unroll
        for (int mt = 0; mt < 4; ++mt)
          HLOAD(hc[c][mt], hbase + (size_t)(mt * 16 + l15) * 1024 + kc + c * 32);

      #pragma unroll
      for (int kk = 0; kk < 8; ++kk){
        if (kk < 5){
          #pragma unroll
          for (int mt = 0; mt < 4; ++mt)
            HLOAD(hc[kk + 3][mt], hbase + (size_t)(mt * 16 + l15) * 1024 + kc + (kk + 3) * 32);
          asm volatile("s_waitcnt vmcnt(12)" ::: "memory");   // chunk kk done, 3 in flight
        } else if (kk == 5) asm volatile("s_waitcnt vmcnt(8)" ::: "memory");
        else if   (kk == 6) asm volatile("s_waitcnt vmcnt(4)" ::: "memory");
        else                asm volatile("s_waitcnt vmcnt(0)" ::: "memory");
        __builtin_amdgcn_sched_barrier(0);
        #pragma unroll
        for (int g = 0; g < 3; ++g)
          #pragma unroll
          for (int mt = 0; mt < 4; ++mt)
            acc[g][mt] = __builtin_amdgcn_mfma_f32_16x16x32_bf16(hc[kk][mt], bfr[g][kk], acc[g][mt], 0, 0, 0);
      }
    }

    // write partial sums to LDS (m-contiguous, swizzled)
    #pragma unroll
    for (int g = 0; g < 3; ++g)
      #pragma unroll
      for (int mt = 0; mt < 4; ++mt)
        *(f32x4*)&red[ridx(wid, g * 16 + l15, mt * 16 + l4 * 4)] = acc[g][mt];
    __syncthreads();

    // reduce over 4 waves; thread -> (row gm, cols g4*4..+3)
    float ra[4] = {}, za[4] = {}, na[4] = {};
    #pragma unroll
    for (int w = 0; w < 4; ++w)
      #pragma unroll
      for (int j = 0; j < 4; ++j){
        ra[j] += red[ridx(w,      g4 * 4 + j, gm)];
        za[j] += red[ridx(w, 16 + g4 * 4 + j, gm)];
        na[j] += red[ridx(w, 32 + g4 * 4 + j, gm)];
      }

    u64 hv = 0;
    float hn[4];
    #pragma unroll
    for (int j = 0; j < 4; ++j){
      float xr = bf2f((uint16_t)(pxr >> (16 * j)));
      float xz = bf2f((uint16_t)(pxz >> (16 * j)));
      float xn = bf2f((uint16_t)(pxn >> (16 * j)));
      float r = 1.f / (1.f + __expf(-(xr + ra[j])));
      float z = 1.f / (1.f + __expf(-(xz + za[j])));
      float n = tanhf(xn + r * (na[j] + bnv[j]));
      hn[j] = (1.f - z) * n + z * hold[j];
      hold[j] = hn[j];
      hv |= ((u64)f2bf(hn[j])) << (16 * j);
    }

    // h store first (agent-relaxed atomic, reaches coherence point), minimal drain
    {
      u64* hw = hbuf + (size_t)(((par ^ 1) * 2) + dir) * (64 * 256);
      __hip_atomic_store(&hw[(size_t)gm * 256 + (c0 >> 2) + g4], hv, __ATOMIC_RELAXED, __HIP_MEMORY_SCOPE_AGENT);
    }
    asm volatile("s_waitcnt vmcnt(0)" ::: "memory");   // h store committed (per wave)
    __syncthreads();                                   // all waves committed
    if (s < 255 && tid == 0)
      __hip_atomic_store(&myflags[blkc * 4], (unsigned)(s + 1), __ATOMIC_RELAXED, __HIP_MEMORY_SCOPE_AGENT);
    __builtin_amdgcn_sched_barrier(0);

    // output stores + next xp prefetch AFTER the flag (overlap with others' polls)
    {
      size_t obase = ((size_t)t * 64 + gm) * 2048 + (size_t)dir * 1024 + gc;
      if (out_bf) __builtin_nontemporal_store(hv, (u64*)&out_bf[obase]);
      else {
        f32x4 ov = { hn[0], hn[1], hn[2], hn[3] };
        __builtin_nontemporal_store(ov, (f32x4*)&out_f32[obase]);
      }
      if (s == 255){
        f32x4 hvv = { hn[0], hn[1], hn[2], hn[3] };
        *(f32x4*)&hid[((size_t)dir * 64 + gm) * 1024 + gc] = hvv;
      }
    }
    if (s < 255){
      int tn = dir ? (255 - (s + 1)) : (s + 1);
      size_t xb2 = ((size_t)tn * 64 + gm) * 3072 + gc;
      pxr = *(const u64*)&xp[xb2];
      pxz = *(const u64*)&xp[xb2 + 1024];
      pxn = *(const u64*)&xp[xb2 + 2048];
    }
  }
}

// ---------- host ----------
extern "C" void kernel_launch(void* const* d_in, const int* in_sizes, int n_in,
                              void* d_out, int out_size, void* d_ws, size_t ws_size,
                              hipStream_t stream) {
  const float* x   = (const float*)d_in[0];
  const float* W0  = (const float*)d_in[1];
  const float* b0  = (const float*)d_in[2];
  const float* Ur0 = (const float*)d_in[3];
  const float* Uz0 = (const float*)d_in[4];
  const float* Un0 = (const float*)d_in[5];
  const float* bn0 = (const float*)d_in[6];
  const float* W1  = (const float*)d_in[7];
  const float* b1  = (const float*)d_in[8];
  const float* Ur1 = (const float*)d_in[9];
  const float* Uz1 = (const float*)d_in[10];
  const float* Un1 = (const float*)d_in[11];
  const float* bn1 = (const float*)d_in[12];
  float* out = (float*)d_out;

  char* base = (char*)d_ws;
  unsigned* ctr0 = (unsigned*)base;                  // layer0 flags (2 dirs * 1KB)
  unsigned* ctr1 = (unsigned*)(base + 4096);         // layer1 flags
  uint16_t* xb    = (uint16_t*)(base + 8192);
  uint16_t* w0b   = xb    + (size_t)16384 * 1024;
  uint16_t* u0b   = w0b   + (size_t)3072 * 1024;
  uint16_t* w1b   = u0b   + (size_t)3072 * 1024;
  uint16_t* u1b   = w1b   + (size_t)3072 * 2048;
  uint16_t* xp    = u1b   + (size_t)3072 * 1024;
  uint16_t* out0b = xp    + (size_t)16384 * 3072;
  u64*      hbuf  = (u64*)(out0b + (size_t)16384 * 2048);

  hipMemsetAsync(d_ws, 0, 8192, stream);

  auto cvt = [&](const float* s, uint16_t* d, size_t n){
    int n4 = (int)(n / 4);
    int grid = (n4 + 255) / 256; if (grid > 2048) grid = 2048;
    hipLaunchKernelGGL(cvt_f32_bf16, dim3(grid), dim3(256), 0, stream, s, d, n4);
  };
  cvt(x,   xb,  (size_t)16384 * 1024);
  cvt(W0,  w0b, (size_t)3072 * 1024);
  cvt(Ur0, u0b + 0 * (size_t)1024 * 1024, (size_t)1024 * 1024);
  cvt(Uz0, u0b + 1 * (size_t)1024 * 1024, (size_t)1024 * 1024);
  cvt(Un0, u0b + 2 * (size_t)1024 * 1024, (size_t)1024 * 1024);
  cvt(W1,  w1b, (size_t)3072 * 2048);
  cvt(Ur1, u1b + 0 * (size_t)1024 * 1024, (size_t)1024 * 1024);
  cvt(Uz1, u1b + 1 * (size_t)1024 * 1024, (size_t)1024 * 1024);
  cvt(Un1, u1b + 2 * (size_t)1024 * 1024, (size_t)1024 * 1024);

  // layer 0: xp0 = x @ W0^T + b0
  hipLaunchKernelGGL(gemm_bt_bias, dim3(24, 128), dim3(256), 0, stream,
                     xb, w0b, b0, xp, 16384, 3072, 1024);
  // layer 0 recurrence -> out0b (bf16), hidden slots 0,1
  hipLaunchKernelGGL(gru_layer, dim3(128), dim3(256), 0, stream,
                     xp, u0b, bn0, hbuf,
                     out0b, (float*)nullptr,
                     out + (size_t)33554432, ctr0);
  // layer 1: xp1 = out0 @ W1^T + b1
  hipLaunchKernelGGL(gemm_bt_bias, dim3(24, 128), dim3(256), 0, stream,
                     out0b, w1b, b1, xp, 16384, 3072, 2048);
  // layer 1 recurrence -> d_out (f32), hidden slots 2,3
  hipLaunchKernelGGL(gru_layer, dim3(128), dim3(256), 0, stream,
                     xp, u1b, bn1, hbuf,
                     (uint16_t*)nullptr, out,
                     out + (size_t)33554432 + (size_t)2 * 64 * 1024, ctr1);
}